// Round 8
// baseline (635.486 us; speedup 1.0000x reference)
//
#include <hip/hip_runtime.h>
#include <cstdint>
#include <cstddef>

typedef _Float16 half8 __attribute__((ext_vector_type(8)));
typedef _Float16 half4 __attribute__((ext_vector_type(4)));
typedef float f32x4 __attribute__((ext_vector_type(4)));

#define MFMA16(A,B,C) __builtin_amdgcn_mfma_f32_16x16x32_f16(A,B,C,0,0,0)

// global -> LDS direct copy, 16B per lane: lds dest = uniform base + lane*16
__device__ __forceinline__ void gll16(const _Float16* g, _Float16* l) {
    __builtin_amdgcn_global_load_lds(
        (const __attribute__((address_space(1))) void*)g,
        (__attribute__((address_space(3))) void*)l, 16, 0, 0);
}

// ---------------- K0: bulk f32 -> f16 convert (X, Wi, Wo) ----------------
__global__ __launch_bounds__(256) void cvt_f16(
    const float* __restrict__ X, const float* __restrict__ Wi, const float* __restrict__ Wo,
    _Float16* __restrict__ Xh, _Float16* __restrict__ Wih, _Float16* __restrict__ Woh)
{
    const size_t i8 = ((size_t)blockIdx.x * 256 + threadIdx.x) * 8;
    const size_t NX = (size_t)4194304, NWI = 786432;
    const float* src; _Float16* dst; size_t off;
    if (i8 < NX) { src = X; dst = Xh; off = i8; }
    else if (i8 < NX + NWI) { src = Wi; dst = Wih; off = i8 - NX; }
    else { src = Wo; dst = Woh; off = i8 - NX - NWI; }
    f32x4 v0 = *(const f32x4*)(src + off);
    f32x4 v1 = *(const f32x4*)(src + off + 4);
    half8 r;
    r[0]=(_Float16)v0[0]; r[1]=(_Float16)v0[1]; r[2]=(_Float16)v0[2]; r[3]=(_Float16)v0[3];
    r[4]=(_Float16)v1[0]; r[5]=(_Float16)v1[1]; r[6]=(_Float16)v1[2]; r[7]=(_Float16)v1[3];
    *(half8*)(dst + off) = r;
}

// ---------------- K1: QKV projection (f16 MFMA, f16 inputs) ----------------
// V^T written PRE-PERMUTED within each 32-col group: s -> (s&~31)|8g|4hi|j
__global__ __launch_bounds__(256) void qkv_mfma(
    const _Float16* __restrict__ X, const _Float16* __restrict__ W,
    const float* __restrict__ bias, const float* __restrict__ gate,
    _Float16* __restrict__ Qo, _Float16* __restrict__ Ko, _Float16* __restrict__ Vt)
{
    __shared__ _Float16 As[128][72];
    __shared__ _Float16 Bs[64][72];
    const int tid = threadIdx.x;
    const int lane = tid & 63, wv = tid >> 6;
    const int l15 = lane & 15, g = lane >> 4;
    const int wr = wv >> 1, wc = wv & 1;
    const int j0 = blockIdx.x * 64, r0 = blockIdx.y * 128;
    f32x4 acc[4][2] = {};
    const int arow = tid >> 1, ahf = tid & 1;
    const int brow = tid >> 2, bc = tid & 3;
    for (int k0 = 0; k0 < 512; k0 += 64) {
        const _Float16* srca = X + (size_t)(r0 + arow) * 512 + k0 + ahf * 32;
#pragma unroll
        for (int c = 0; c < 4; ++c)
            *(half8*)&As[arow][ahf * 32 + c * 8] = *(const half8*)(srca + c * 8);
        const _Float16* srcb = W + (size_t)(j0 + brow) * 512 + k0 + bc * 16;
#pragma unroll
        for (int c = 0; c < 2; ++c)
            *(half8*)&Bs[brow][bc * 16 + c * 8] = *(const half8*)(srcb + c * 8);
        __syncthreads();
#pragma unroll
        for (int kt = 0; kt < 2; ++kt) {
            half8 bf0 = *(half8*)&Bs[32 * wc + l15][kt * 32 + g * 8];
            half8 bf1 = *(half8*)&Bs[32 * wc + 16 + l15][kt * 32 + g * 8];
#pragma unroll
            for (int ri = 0; ri < 4; ++ri) {
                half8 af = *(half8*)&As[64 * wr + 16 * ri + l15][kt * 32 + g * 8];
                acc[ri][0] = MFMA16(af, bf0, acc[ri][0]);
                acc[ri][1] = MFMA16(af, bf1, acc[ri][1]);
            }
        }
        __syncthreads();
    }
#pragma unroll
    for (int ri = 0; ri < 4; ++ri) {
#pragma unroll
        for (int cj = 0; cj < 2; ++cj) {
            const int col = j0 + 32 * wc + 16 * cj + l15;
            const int sec = col >> 9, hh = (col >> 6) & 7, d = col & 63;
            const float bv = bias[col];
#pragma unroll
            for (int r = 0; r < 4; ++r) {
                const int row = r0 + 64 * wr + 16 * ri + 4 * g + r;
                const int b = row & 3, s = row >> 2;
                const float v = acc[ri][cj][r];
                if (sec == 0)
                    Qo[((size_t)(b * 8 + hh) * 2048 + s) * 64 + d] = (_Float16)((v + bv) * 0.125f);
                else if (sec == 1)
                    Ko[((size_t)(b * 8 + hh) * 2048 + s) * 64 + d] = (_Float16)(v + bv);
                else {
                    const int ps = (s & ~31) | ((s & 12) << 1) | ((s & 16) >> 2) | (s & 3);
                    Vt[((size_t)(b * 8 + hh) * 64 + d) * 2048 + ps] = (_Float16)(v * gate[b] + bv);
                }
            }
        }
    }
}

// ---------------- K2: flash attention, 4-wave blocks, kv-split 4 ----------------
__global__ __launch_bounds__(256, 4) void attn_mfma(
    const _Float16* __restrict__ Q, const _Float16* __restrict__ K,
    const _Float16* __restrict__ V, const float* __restrict__ M,
    _Float16* __restrict__ P0, _Float16* __restrict__ P1,
    _Float16* __restrict__ P2, _Float16* __restrict__ P3, float* __restrict__ Lb)
{
    __shared__ _Float16 Kl[2][4096];
    __shared__ _Float16 Vl[2][4096];
    const int tid = threadIdx.x;
    const int lane = tid & 63, w = tid >> 6;
    const int l15 = lane & 15, g = lane >> 4;
    const int bsw = l15 & 7;
    const int bid = blockIdx.x;
    const int h = bid & 7, b = (bid >> 3) & 3, sg = (bid >> 5) & 7, kvh = bid >> 8;
    const int s0 = sg * 256 + w * 64;
    const size_t bh = (size_t)b * 8 + h;
    const _Float16* Qp = Q + bh * 2048 * 64;
    const _Float16* Kp = K + bh * 2048 * 64 + (size_t)kvh * 512 * 64;
    const _Float16* Vp = V + bh * 64 * 2048 + kvh * 512;   // permuted [d][s]
    const float* Mp = M + (size_t)h * 2048 * 2048 + kvh * 512;

    half8 qf[4][2];
#pragma unroll
    for (int qj = 0; qj < 4; ++qj)
#pragma unroll
        for (int dh = 0; dh < 2; ++dh)
            qf[qj][dh] = *(const half8*)(Qp + (size_t)(s0 + 16 * qj + l15) * 64 + dh * 32 + g * 8);

    const int grow = lane >> 3, gcb = lane & 7;
    const int hw = w & 1;
    const bool stK = (w < 2);

    if (stK) {
#pragma unroll
        for (int c = 0; c < 4; ++c) {
            const int r = hw * 32 + c * 8 + grow;
            gll16(Kp + (size_t)r * 64 + ((gcb ^ (r & 7)) * 8), &Kl[0][hw * 2048 + c * 512]);
        }
    } else {
#pragma unroll
        for (int c = 0; c < 4; ++c) {
            const int d = hw * 32 + c * 8 + grow;
            gll16(Vp + (size_t)d * 2048 + ((gcb ^ (d & 7)) * 8), &Vl[0][hw * 2048 + c * 512]);
        }
    }
    f32x4 mc0[2][4], mc1[2][4];
#pragma unroll
    for (int mi = 0; mi < 2; ++mi)
#pragma unroll
        for (int qj = 0; qj < 4; ++qj)
            mc0[mi][qj] = *(const f32x4*)(Mp + (size_t)(s0 + 16 * qj + l15) * 2048 + 16 * mi + 4 * g);

    f32x4 O[4][4] = {};
    float l[4] = {0.f, 0.f, 0.f, 0.f};
    __syncthreads();

    for (int tl = 0; tl < 8; ++tl) {
        const int cur = tl & 1;
        const int t0 = tl * 64;
        const int tn = ((tl + 1) & 7) * 64;
        if (tl < 7) {
            if (stK) {
#pragma unroll
                for (int c = 0; c < 4; ++c) {
                    const int r = hw * 32 + c * 8 + grow;
                    gll16(Kp + (size_t)(t0 + 64 + r) * 64 + ((gcb ^ (r & 7)) * 8),
                          &Kl[cur ^ 1][hw * 2048 + c * 512]);
                }
            } else {
#pragma unroll
                for (int c = 0; c < 4; ++c) {
                    const int d = hw * 32 + c * 8 + grow;
                    gll16(Vp + (size_t)d * 2048 + t0 + 64 + ((gcb ^ (d & 7)) * 8),
                          &Vl[cur ^ 1][hw * 2048 + c * 512]);
                }
            }
        }

        f32x4 St[2][4];
        __builtin_amdgcn_s_setprio(1);
#pragma unroll
        for (int mi = 0; mi < 2; ++mi) {
            const int row = 16 * mi + l15;
            half8 kf0 = *(half8*)&Kl[cur][row * 64 + ((g) ^ bsw) * 8];
            half8 kf1 = *(half8*)&Kl[cur][row * 64 + ((4 + g) ^ bsw) * 8];
#pragma unroll
            for (int qj = 0; qj < 4; ++qj) {
                St[mi][qj] = MFMA16(kf0, qf[qj][0], mc0[mi][qj]);
                St[mi][qj] = MFMA16(kf1, qf[qj][1], St[mi][qj]);
            }
        }
        __builtin_amdgcn_s_setprio(0);
#pragma unroll
        for (int mi = 0; mi < 2; ++mi)
#pragma unroll
            for (int qj = 0; qj < 4; ++qj)
                mc1[mi][qj] = *(const f32x4*)(Mp + (size_t)(s0 + 16 * qj + l15) * 2048 + t0 + 16 * (2 + mi) + 4 * g);
        half8 pfA[4];
#pragma unroll
        for (int qj = 0; qj < 4; ++qj) {
            float e00 = __expf(St[0][qj][0]), e01 = __expf(St[0][qj][1]);
            float e02 = __expf(St[0][qj][2]), e03 = __expf(St[0][qj][3]);
            float e10 = __expf(St[1][qj][0]), e11 = __expf(St[1][qj][1]);
            float e12 = __expf(St[1][qj][2]), e13 = __expf(St[1][qj][3]);
            l[qj] += ((e00 + e01) + (e02 + e03)) + ((e10 + e11) + (e12 + e13));
            half8 p;
            p[0] = (_Float16)e00; p[1] = (_Float16)e01; p[2] = (_Float16)e02; p[3] = (_Float16)e03;
            p[4] = (_Float16)e10; p[5] = (_Float16)e11; p[6] = (_Float16)e12; p[7] = (_Float16)e13;
            pfA[qj] = p;
        }
        __builtin_amdgcn_s_setprio(1);
#pragma unroll
        for (int di = 0; di < 4; ++di) {
            const int vrow = 16 * di + l15;
            half8 vf = *(half8*)&Vl[cur][vrow * 64 + ((g) ^ bsw) * 8];
#pragma unroll
            for (int qj = 0; qj < 4; ++qj)
                O[di][qj] = MFMA16(vf, pfA[qj], O[di][qj]);
        }
        __builtin_amdgcn_s_setprio(0);

        __builtin_amdgcn_s_setprio(1);
#pragma unroll
        for (int mi = 0; mi < 2; ++mi) {
            const int row = 16 * (2 + mi) + l15;
            half8 kf0 = *(half8*)&Kl[cur][row * 64 + ((g) ^ bsw) * 8];
            half8 kf1 = *(half8*)&Kl[cur][row * 64 + ((4 + g) ^ bsw) * 8];
#pragma unroll
            for (int qj = 0; qj < 4; ++qj) {
                St[mi][qj] = MFMA16(kf0, qf[qj][0], mc1[mi][qj]);
                St[mi][qj] = MFMA16(kf1, qf[qj][1], St[mi][qj]);
            }
        }
        __builtin_amdgcn_s_setprio(0);
#pragma unroll
        for (int mi = 0; mi < 2; ++mi)
#pragma unroll
            for (int qj = 0; qj < 4; ++qj)
                mc0[mi][qj] = *(const f32x4*)(Mp + (size_t)(s0 + 16 * qj + l15) * 2048 + tn + 16 * mi + 4 * g);
        half8 pfB[4];
#pragma unroll
        for (int qj = 0; qj < 4; ++qj) {
            float e00 = __expf(St[0][qj][0]), e01 = __expf(St[0][qj][1]);
            float e02 = __expf(St[0][qj][2]), e03 = __expf(St[0][qj][3]);
            float e10 = __expf(St[1][qj][0]), e11 = __expf(St[1][qj][1]);
            float e12 = __expf(St[1][qj][2]), e13 = __expf(St[1][qj][3]);
            l[qj] += ((e00 + e01) + (e02 + e03)) + ((e10 + e11) + (e12 + e13));
            half8 p;
            p[0] = (_Float16)e00; p[1] = (_Float16)e01; p[2] = (_Float16)e02; p[3] = (_Float16)e03;
            p[4] = (_Float16)e10; p[5] = (_Float16)e11; p[6] = (_Float16)e12; p[7] = (_Float16)e13;
            pfB[qj] = p;
        }
        __builtin_amdgcn_s_setprio(1);
#pragma unroll
        for (int di = 0; di < 4; ++di) {
            const int vrow = 16 * di + l15;
            half8 vf = *(half8*)&Vl[cur][vrow * 64 + ((4 + g) ^ bsw) * 8];
#pragma unroll
            for (int qj = 0; qj < 4; ++qj)
                O[di][qj] = MFMA16(vf, pfB[qj], O[di][qj]);
        }
        __builtin_amdgcn_s_setprio(0);

        __syncthreads();
    }

    _Float16* P = (kvh == 0) ? P0 : (kvh == 1) ? P1 : (kvh == 2) ? P2 : P3;
#pragma unroll
    for (int qj = 0; qj < 4; ++qj) {
        float lt = l[qj];
        lt += __shfl_xor(lt, 16);
        lt += __shfl_xor(lt, 32);
        const float inv = 1.0f / lt;
        const int q = s0 + 16 * qj + l15;
        const int r = q * 4 + b;
        _Float16* dst = P + (size_t)r * 512 + h * 64;
#pragma unroll
        for (int di = 0; di < 4; ++di) {
            half4 o;
            o[0] = (_Float16)(O[di][qj][0] * inv); o[1] = (_Float16)(O[di][qj][1] * inv);
            o[2] = (_Float16)(O[di][qj][2] * inv); o[3] = (_Float16)(O[di][qj][3] * inv);
            *(half4*)(dst + 16 * di + 4 * g) = o;
        }
        if (g == 0)
            Lb[(size_t)kvh * 65536 + r * 8 + h] = lt;
    }
}

// ---------------- K3: output projection with fused 4-way partial merge ----------------
__global__ __launch_bounds__(256) void oproj_mfma(
    const _Float16* __restrict__ P0, const _Float16* __restrict__ P1,
    const _Float16* __restrict__ P2, const _Float16* __restrict__ P3,
    const float* __restrict__ Lb, const _Float16* __restrict__ W,
    const float* __restrict__ bias, float* __restrict__ Out)
{
    __shared__ _Float16 As[128][72];
    __shared__ _Float16 Bs[64][72];
    const int tid = threadIdx.x;
    const int lane = tid & 63, wv = tid >> 6;
    const int l15 = lane & 15, g = lane >> 4;
    const int wr = wv >> 1, wc = wv & 1;
    const int j0 = blockIdx.x * 64, r0 = blockIdx.y * 128;
    f32x4 acc[4][2] = {};
    const int arow = tid >> 1, ahf = tid & 1;
    const int brow = tid >> 2, bc = tid & 3;
    for (int k0 = 0; k0 < 512; k0 += 64) {
        const int row = r0 + arow;
        const int li = row * 8 + (k0 >> 6);
        const float l0 = Lb[li], l1 = Lb[65536 + li], l2 = Lb[131072 + li], l3 = Lb[196608 + li];
        const float inv = 1.0f / (l0 + l1 + l2 + l3);
        const float w0 = l0 * inv, w1 = l1 * inv, w2 = l2 * inv, w3 = l3 * inv;
        const size_t abase = (size_t)row * 512 + k0 + ahf * 32;
#pragma unroll
        for (int c = 0; c < 4; ++c) {
            half8 x0 = *(const half8*)(P0 + abase + c * 8);
            half8 x1 = *(const half8*)(P1 + abase + c * 8);
            half8 x2 = *(const half8*)(P2 + abase + c * 8);
            half8 x3 = *(const half8*)(P3 + abase + c * 8);
            half8 r;
#pragma unroll
            for (int i = 0; i < 8; ++i)
                r[i] = (_Float16)(w0 * (float)x0[i] + w1 * (float)x1[i]
                                + w2 * (float)x2[i] + w3 * (float)x3[i]);
            *(half8*)&As[arow][ahf * 32 + c * 8] = r;
        }
        const _Float16* srcb = W + (size_t)(j0 + brow) * 512 + k0 + bc * 16;
#pragma unroll
        for (int c = 0; c < 2; ++c)
            *(half8*)&Bs[brow][bc * 16 + c * 8] = *(const half8*)(srcb + c * 8);
        __syncthreads();
#pragma unroll
        for (int kt = 0; kt < 2; ++kt) {
            half8 bf0 = *(half8*)&Bs[32 * wc + l15][kt * 32 + g * 8];
            half8 bf1 = *(half8*)&Bs[32 * wc + 16 + l15][kt * 32 + g * 8];
#pragma unroll
            for (int ri = 0; ri < 4; ++ri) {
                half8 af = *(half8*)&As[64 * wr + 16 * ri + l15][kt * 32 + g * 8];
                acc[ri][0] = MFMA16(af, bf0, acc[ri][0]);
                acc[ri][1] = MFMA16(af, bf1, acc[ri][1]);
            }
        }
        __syncthreads();
    }
#pragma unroll
    for (int ri = 0; ri < 4; ++ri) {
#pragma unroll
        for (int cj = 0; cj < 2; ++cj) {
            const int col = j0 + 32 * wc + 16 * cj + l15;
            const float bv = bias[col];
#pragma unroll
            for (int r = 0; r < 4; ++r) {
                const int row = r0 + 64 * wr + 16 * ri + 4 * g + r;
                Out[(size_t)row * 512 + col] = acc[ri][cj][r] + bv;
            }
        }
    }
}

extern "C" void kernel_launch(void* const* d_in, const int* in_sizes, int n_in,
                              void* d_out, int out_size, void* d_ws, size_t ws_size,
                              hipStream_t stream)
{
    (void)in_sizes; (void)n_in; (void)out_size; (void)ws_size;
    const float* X    = (const float*)d_in[0];  // (S,B,D)
    const float* Mask = (const float*)d_in[1];  // (H,S,S)
    const float* gate = (const float*)d_in[2];  // (1,B,1)
    const float* Wi   = (const float*)d_in[3];  // (3D,D)
    const float* bi   = (const float*)d_in[4];  // (3D)
    const float* Wo   = (const float*)d_in[5];  // (D,D)
    const float* bo   = (const float*)d_in[6];  // (D)
    _Float16* ws = (_Float16*)d_ws;
    const size_t plane = (size_t)4 * 8 * 2048 * 64;  // 4,194,304 f16 elems
    _Float16* Qh  = ws;
    _Float16* Kh  = ws + plane;
    _Float16* Vt  = ws + 2 * plane;              // pre-permuted V^T
    _Float16* P1  = ws + 3 * plane;              // (was AO; merge fused into oproj)
    _Float16* Xh  = ws + 4 * plane;              // dead after qkv; aliased by P0
    _Float16* Wih = ws + 5 * plane;              // 786,432 (dead after qkv)
    _Float16* Woh = ws + 5 * plane + 786432;     // 262,144 (live until oproj)
    _Float16* P0  = Xh;
    _Float16* P2  = ws + 5 * plane + 1048576;
    _Float16* P3  = P2 + plane;
    float*    Lb  = (float*)(P3 + plane);        // 4*65536 f32

    cvt_f16<<<dim3(2560), 256, 0, stream>>>(X, Wi, Wo, Xh, Wih, Woh);
    qkv_mfma<<<dim3(24, 64), 256, 0, stream>>>(Xh, Wih, bi, gate, Qh, Kh, Vt);
    attn_mfma<<<dim3(1024), 256, 0, stream>>>(Qh, Kh, Vt, Mask, P0, P1, P2, P3, Lb);
    oproj_mfma<<<dim3(8, 64), 256, 0, stream>>>(P0, P1, P2, P3, Lb, Woh, bo, (float*)d_out);
}

// Round 9
// 204.106 us; speedup vs baseline: 3.1135x; 3.1135x over previous
//
#include <hip/hip_runtime.h>
#include <cstdint>
#include <cstddef>

typedef _Float16 half8 __attribute__((ext_vector_type(8)));
typedef _Float16 half4 __attribute__((ext_vector_type(4)));
typedef float f32x4 __attribute__((ext_vector_type(4)));

#define MFMA16(A,B,C) __builtin_amdgcn_mfma_f32_16x16x32_f16(A,B,C,0,0,0)

// global -> LDS direct copy, 16B per lane: lds dest = uniform base + lane*16
__device__ __forceinline__ void gll16(const _Float16* g, _Float16* l) {
    __builtin_amdgcn_global_load_lds(
        (const __attribute__((address_space(1))) void*)g,
        (__attribute__((address_space(3))) void*)l, 16, 0, 0);
}

// ---------------- K0: bulk f32 -> f16 convert (X, Wi, Wo) ----------------
__global__ __launch_bounds__(256) void cvt_f16(
    const float* __restrict__ X, const float* __restrict__ Wi, const float* __restrict__ Wo,
    _Float16* __restrict__ Xh, _Float16* __restrict__ Wih, _Float16* __restrict__ Woh)
{
    const size_t i8 = ((size_t)blockIdx.x * 256 + threadIdx.x) * 8;
    const size_t NX = (size_t)4194304, NWI = 786432;
    const float* src; _Float16* dst; size_t off;
    if (i8 < NX) { src = X; dst = Xh; off = i8; }
    else if (i8 < NX + NWI) { src = Wi; dst = Wih; off = i8 - NX; }
    else { src = Wo; dst = Woh; off = i8 - NX - NWI; }
    f32x4 v0 = *(const f32x4*)(src + off);
    f32x4 v1 = *(const f32x4*)(src + off + 4);
    half8 r;
    r[0]=(_Float16)v0[0]; r[1]=(_Float16)v0[1]; r[2]=(_Float16)v0[2]; r[3]=(_Float16)v0[3];
    r[4]=(_Float16)v1[0]; r[5]=(_Float16)v1[1]; r[6]=(_Float16)v1[2]; r[7]=(_Float16)v1[3];
    *(half8*)(dst + off) = r;
}

// ---------------- K1: QKV projection (f16 MFMA, f16 inputs) ----------------
// V^T written PRE-PERMUTED within each 32-col group: s -> (s&~31)|8g|4hi|j
__global__ __launch_bounds__(256) void qkv_mfma(
    const _Float16* __restrict__ X, const _Float16* __restrict__ W,
    const float* __restrict__ bias, const float* __restrict__ gate,
    _Float16* __restrict__ Qo, _Float16* __restrict__ Ko, _Float16* __restrict__ Vt)
{
    __shared__ _Float16 As[128][72];
    __shared__ _Float16 Bs[64][72];
    const int tid = threadIdx.x;
    const int lane = tid & 63, wv = tid >> 6;
    const int l15 = lane & 15, g = lane >> 4;
    const int wr = wv >> 1, wc = wv & 1;
    const int j0 = blockIdx.x * 64, r0 = blockIdx.y * 128;
    f32x4 acc[4][2] = {};
    const int arow = tid >> 1, ahf = tid & 1;
    const int brow = tid >> 2, bc = tid & 3;
    for (int k0 = 0; k0 < 512; k0 += 64) {
        const _Float16* srca = X + (size_t)(r0 + arow) * 512 + k0 + ahf * 32;
#pragma unroll
        for (int c = 0; c < 4; ++c)
            *(half8*)&As[arow][ahf * 32 + c * 8] = *(const half8*)(srca + c * 8);
        const _Float16* srcb = W + (size_t)(j0 + brow) * 512 + k0 + bc * 16;
#pragma unroll
        for (int c = 0; c < 2; ++c)
            *(half8*)&Bs[brow][bc * 16 + c * 8] = *(const half8*)(srcb + c * 8);
        __syncthreads();
#pragma unroll
        for (int kt = 0; kt < 2; ++kt) {
            half8 bf0 = *(half8*)&Bs[32 * wc + l15][kt * 32 + g * 8];
            half8 bf1 = *(half8*)&Bs[32 * wc + 16 + l15][kt * 32 + g * 8];
#pragma unroll
            for (int ri = 0; ri < 4; ++ri) {
                half8 af = *(half8*)&As[64 * wr + 16 * ri + l15][kt * 32 + g * 8];
                acc[ri][0] = MFMA16(af, bf0, acc[ri][0]);
                acc[ri][1] = MFMA16(af, bf1, acc[ri][1]);
            }
        }
        __syncthreads();
    }
#pragma unroll
    for (int ri = 0; ri < 4; ++ri) {
#pragma unroll
        for (int cj = 0; cj < 2; ++cj) {
            const int col = j0 + 32 * wc + 16 * cj + l15;
            const int sec = col >> 9, hh = (col >> 6) & 7, d = col & 63;
            const float bv = bias[col];
#pragma unroll
            for (int r = 0; r < 4; ++r) {
                const int row = r0 + 64 * wr + 16 * ri + 4 * g + r;
                const int b = row & 3, s = row >> 2;
                const float v = acc[ri][cj][r];
                if (sec == 0)
                    Qo[((size_t)(b * 8 + hh) * 2048 + s) * 64 + d] = (_Float16)((v + bv) * 0.125f);
                else if (sec == 1)
                    Ko[((size_t)(b * 8 + hh) * 2048 + s) * 64 + d] = (_Float16)(v + bv);
                else {
                    const int ps = (s & ~31) | ((s & 12) << 1) | ((s & 16) >> 2) | (s & 3);
                    Vt[((size_t)(b * 8 + hh) * 64 + d) * 2048 + ps] = (_Float16)(v * gate[b] + bv);
                }
            }
        }
    }
}

// ---------------- K2: flash attention, 4-wave blocks, kv-split 4 ----------------
// NO min-wave launch bound: R5/R8 showed a forced VGPR cap (64) spills the
// accumulators -> 1.2 GB scratch traffic. Natural alloc ~120 VGPR gives
// 4 waves/SIMD anyway (<=128) with zero spill.
__global__ __launch_bounds__(256) void attn_mfma(
    const _Float16* __restrict__ Q, const _Float16* __restrict__ K,
    const _Float16* __restrict__ V, const float* __restrict__ M,
    _Float16* __restrict__ P0, _Float16* __restrict__ P1,
    _Float16* __restrict__ P2, _Float16* __restrict__ P3, float* __restrict__ Lb)
{
    __shared__ _Float16 Kl[2][4096];
    __shared__ _Float16 Vl[2][4096];
    const int tid = threadIdx.x;
    const int lane = tid & 63, w = tid >> 6;
    const int l15 = lane & 15, g = lane >> 4;
    const int bsw = l15 & 7;
    const int bid = blockIdx.x;
    const int h = bid & 7, b = (bid >> 3) & 3, sg = (bid >> 5) & 7, kvh = bid >> 8;
    const int s0 = sg * 256 + w * 64;
    const size_t bh = (size_t)b * 8 + h;
    const _Float16* Qp = Q + bh * 2048 * 64;
    const _Float16* Kp = K + bh * 2048 * 64 + (size_t)kvh * 512 * 64;
    const _Float16* Vp = V + bh * 64 * 2048 + kvh * 512;   // permuted [d][s]
    const float* Mp = M + (size_t)h * 2048 * 2048 + kvh * 512;

    half8 qf[4][2];
#pragma unroll
    for (int qj = 0; qj < 4; ++qj)
#pragma unroll
        for (int dh = 0; dh < 2; ++dh)
            qf[qj][dh] = *(const half8*)(Qp + (size_t)(s0 + 16 * qj + l15) * 64 + dh * 32 + g * 8);

    const int grow = lane >> 3, gcb = lane & 7;
    const int hw = w & 1;
    const bool stK = (w < 2);

    if (stK) {
#pragma unroll
        for (int c = 0; c < 4; ++c) {
            const int r = hw * 32 + c * 8 + grow;
            gll16(Kp + (size_t)r * 64 + ((gcb ^ (r & 7)) * 8), &Kl[0][hw * 2048 + c * 512]);
        }
    } else {
#pragma unroll
        for (int c = 0; c < 4; ++c) {
            const int d = hw * 32 + c * 8 + grow;
            gll16(Vp + (size_t)d * 2048 + ((gcb ^ (d & 7)) * 8), &Vl[0][hw * 2048 + c * 512]);
        }
    }
    f32x4 mc0[2][4], mc1[2][4];
#pragma unroll
    for (int mi = 0; mi < 2; ++mi)
#pragma unroll
        for (int qj = 0; qj < 4; ++qj)
            mc0[mi][qj] = *(const f32x4*)(Mp + (size_t)(s0 + 16 * qj + l15) * 2048 + 16 * mi + 4 * g);

    f32x4 O[4][4] = {};
    float l[4] = {0.f, 0.f, 0.f, 0.f};
    __syncthreads();

    for (int tl = 0; tl < 8; ++tl) {
        const int cur = tl & 1;
        const int t0 = tl * 64;
        const int tn = ((tl + 1) & 7) * 64;
        if (tl < 7) {
            if (stK) {
#pragma unroll
                for (int c = 0; c < 4; ++c) {
                    const int r = hw * 32 + c * 8 + grow;
                    gll16(Kp + (size_t)(t0 + 64 + r) * 64 + ((gcb ^ (r & 7)) * 8),
                          &Kl[cur ^ 1][hw * 2048 + c * 512]);
                }
            } else {
#pragma unroll
                for (int c = 0; c < 4; ++c) {
                    const int d = hw * 32 + c * 8 + grow;
                    gll16(Vp + (size_t)d * 2048 + t0 + 64 + ((gcb ^ (d & 7)) * 8),
                          &Vl[cur ^ 1][hw * 2048 + c * 512]);
                }
            }
        }

        f32x4 St[2][4];
        __builtin_amdgcn_s_setprio(1);
#pragma unroll
        for (int mi = 0; mi < 2; ++mi) {
            const int row = 16 * mi + l15;
            half8 kf0 = *(half8*)&Kl[cur][row * 64 + ((g) ^ bsw) * 8];
            half8 kf1 = *(half8*)&Kl[cur][row * 64 + ((4 + g) ^ bsw) * 8];
#pragma unroll
            for (int qj = 0; qj < 4; ++qj) {
                St[mi][qj] = MFMA16(kf0, qf[qj][0], mc0[mi][qj]);
                St[mi][qj] = MFMA16(kf1, qf[qj][1], St[mi][qj]);
            }
        }
        __builtin_amdgcn_s_setprio(0);
#pragma unroll
        for (int mi = 0; mi < 2; ++mi)
#pragma unroll
            for (int qj = 0; qj < 4; ++qj)
                mc1[mi][qj] = *(const f32x4*)(Mp + (size_t)(s0 + 16 * qj + l15) * 2048 + t0 + 16 * (2 + mi) + 4 * g);
        half8 pfA[4];
#pragma unroll
        for (int qj = 0; qj < 4; ++qj) {
            float e00 = __expf(St[0][qj][0]), e01 = __expf(St[0][qj][1]);
            float e02 = __expf(St[0][qj][2]), e03 = __expf(St[0][qj][3]);
            float e10 = __expf(St[1][qj][0]), e11 = __expf(St[1][qj][1]);
            float e12 = __expf(St[1][qj][2]), e13 = __expf(St[1][qj][3]);
            l[qj] += ((e00 + e01) + (e02 + e03)) + ((e10 + e11) + (e12 + e13));
            half8 p;
            p[0] = (_Float16)e00; p[1] = (_Float16)e01; p[2] = (_Float16)e02; p[3] = (_Float16)e03;
            p[4] = (_Float16)e10; p[5] = (_Float16)e11; p[6] = (_Float16)e12; p[7] = (_Float16)e13;
            pfA[qj] = p;
        }
        __builtin_amdgcn_s_setprio(1);
#pragma unroll
        for (int di = 0; di < 4; ++di) {
            const int vrow = 16 * di + l15;
            half8 vf = *(half8*)&Vl[cur][vrow * 64 + ((g) ^ bsw) * 8];
#pragma unroll
            for (int qj = 0; qj < 4; ++qj)
                O[di][qj] = MFMA16(vf, pfA[qj], O[di][qj]);
        }
        __builtin_amdgcn_s_setprio(0);

        __builtin_amdgcn_s_setprio(1);
#pragma unroll
        for (int mi = 0; mi < 2; ++mi) {
            const int row = 16 * (2 + mi) + l15;
            half8 kf0 = *(half8*)&Kl[cur][row * 64 + ((g) ^ bsw) * 8];
            half8 kf1 = *(half8*)&Kl[cur][row * 64 + ((4 + g) ^ bsw) * 8];
#pragma unroll
            for (int qj = 0; qj < 4; ++qj) {
                St[mi][qj] = MFMA16(kf0, qf[qj][0], mc1[mi][qj]);
                St[mi][qj] = MFMA16(kf1, qf[qj][1], St[mi][qj]);
            }
        }
        __builtin_amdgcn_s_setprio(0);
#pragma unroll
        for (int mi = 0; mi < 2; ++mi)
#pragma unroll
            for (int qj = 0; qj < 4; ++qj)
                mc0[mi][qj] = *(const f32x4*)(Mp + (size_t)(s0 + 16 * qj + l15) * 2048 + tn + 16 * mi + 4 * g);
        half8 pfB[4];
#pragma unroll
        for (int qj = 0; qj < 4; ++qj) {
            float e00 = __expf(St[0][qj][0]), e01 = __expf(St[0][qj][1]);
            float e02 = __expf(St[0][qj][2]), e03 = __expf(St[0][qj][3]);
            float e10 = __expf(St[1][qj][0]), e11 = __expf(St[1][qj][1]);
            float e12 = __expf(St[1][qj][2]), e13 = __expf(St[1][qj][3]);
            l[qj] += ((e00 + e01) + (e02 + e03)) + ((e10 + e11) + (e12 + e13));
            half8 p;
            p[0] = (_Float16)e00; p[1] = (_Float16)e01; p[2] = (_Float16)e02; p[3] = (_Float16)e03;
            p[4] = (_Float16)e10; p[5] = (_Float16)e11; p[6] = (_Float16)e12; p[7] = (_Float16)e13;
            pfB[qj] = p;
        }
        __builtin_amdgcn_s_setprio(1);
#pragma unroll
        for (int di = 0; di < 4; ++di) {
            const int vrow = 16 * di + l15;
            half8 vf = *(half8*)&Vl[cur][vrow * 64 + ((4 + g) ^ bsw) * 8];
#pragma unroll
            for (int qj = 0; qj < 4; ++qj)
                O[di][qj] = MFMA16(vf, pfB[qj], O[di][qj]);
        }
        __builtin_amdgcn_s_setprio(0);

        __syncthreads();
    }

    _Float16* P = (kvh == 0) ? P0 : (kvh == 1) ? P1 : (kvh == 2) ? P2 : P3;
#pragma unroll
    for (int qj = 0; qj < 4; ++qj) {
        float lt = l[qj];
        lt += __shfl_xor(lt, 16);
        lt += __shfl_xor(lt, 32);
        const float inv = 1.0f / lt;
        const int q = s0 + 16 * qj + l15;
        const int r = q * 4 + b;
        _Float16* dst = P + (size_t)r * 512 + h * 64;
#pragma unroll
        for (int di = 0; di < 4; ++di) {
            half4 o;
            o[0] = (_Float16)(O[di][qj][0] * inv); o[1] = (_Float16)(O[di][qj][1] * inv);
            o[2] = (_Float16)(O[di][qj][2] * inv); o[3] = (_Float16)(O[di][qj][3] * inv);
            *(half4*)(dst + 16 * di + 4 * g) = o;
        }
        if (g == 0)
            Lb[(size_t)kvh * 65536 + r * 8 + h] = lt;
    }
}

// ---------------- K3: output projection with fused 4-way partial merge ----------------
__global__ __launch_bounds__(256) void oproj_mfma(
    const _Float16* __restrict__ P0, const _Float16* __restrict__ P1,
    const _Float16* __restrict__ P2, const _Float16* __restrict__ P3,
    const float* __restrict__ Lb, const _Float16* __restrict__ W,
    const float* __restrict__ bias, float* __restrict__ Out)
{
    __shared__ _Float16 As[128][72];
    __shared__ _Float16 Bs[64][72];
    const int tid = threadIdx.x;
    const int lane = tid & 63, wv = tid >> 6;
    const int l15 = lane & 15, g = lane >> 4;
    const int wr = wv >> 1, wc = wv & 1;
    const int j0 = blockIdx.x * 64, r0 = blockIdx.y * 128;
    f32x4 acc[4][2] = {};
    const int arow = tid >> 1, ahf = tid & 1;
    const int brow = tid >> 2, bc = tid & 3;
    for (int k0 = 0; k0 < 512; k0 += 64) {
        const int row = r0 + arow;
        const int li = row * 8 + (k0 >> 6);
        const float l0 = Lb[li], l1 = Lb[65536 + li], l2 = Lb[131072 + li], l3 = Lb[196608 + li];
        const float inv = 1.0f / (l0 + l1 + l2 + l3);
        const float w0 = l0 * inv, w1 = l1 * inv, w2 = l2 * inv, w3 = l3 * inv;
        const size_t abase = (size_t)row * 512 + k0 + ahf * 32;
#pragma unroll
        for (int c = 0; c < 4; ++c) {
            half8 x0 = *(const half8*)(P0 + abase + c * 8);
            half8 x1 = *(const half8*)(P1 + abase + c * 8);
            half8 x2 = *(const half8*)(P2 + abase + c * 8);
            half8 x3 = *(const half8*)(P3 + abase + c * 8);
            half8 r;
#pragma unroll
            for (int i = 0; i < 8; ++i)
                r[i] = (_Float16)(w0 * (float)x0[i] + w1 * (float)x1[i]
                                + w2 * (float)x2[i] + w3 * (float)x3[i]);
            *(half8*)&As[arow][ahf * 32 + c * 8] = r;
        }
        const _Float16* srcb = W + (size_t)(j0 + brow) * 512 + k0 + bc * 16;
#pragma unroll
        for (int c = 0; c < 2; ++c)
            *(half8*)&Bs[brow][bc * 16 + c * 8] = *(const half8*)(srcb + c * 8);
        __syncthreads();
#pragma unroll
        for (int kt = 0; kt < 2; ++kt) {
            half8 bf0 = *(half8*)&Bs[32 * wc + l15][kt * 32 + g * 8];
            half8 bf1 = *(half8*)&Bs[32 * wc + 16 + l15][kt * 32 + g * 8];
#pragma unroll
            for (int ri = 0; ri < 4; ++ri) {
                half8 af = *(half8*)&As[64 * wr + 16 * ri + l15][kt * 32 + g * 8];
                acc[ri][0] = MFMA16(af, bf0, acc[ri][0]);
                acc[ri][1] = MFMA16(af, bf1, acc[ri][1]);
            }
        }
        __syncthreads();
    }
#pragma unroll
    for (int ri = 0; ri < 4; ++ri) {
#pragma unroll
        for (int cj = 0; cj < 2; ++cj) {
            const int col = j0 + 32 * wc + 16 * cj + l15;
            const float bv = bias[col];
#pragma unroll
            for (int r = 0; r < 4; ++r) {
                const int row = r0 + 64 * wr + 16 * ri + 4 * g + r;
                Out[(size_t)row * 512 + col] = acc[ri][cj][r] + bv;
            }
        }
    }
}

extern "C" void kernel_launch(void* const* d_in, const int* in_sizes, int n_in,
                              void* d_out, int out_size, void* d_ws, size_t ws_size,
                              hipStream_t stream)
{
    (void)in_sizes; (void)n_in; (void)out_size; (void)ws_size;
    const float* X    = (const float*)d_in[0];  // (S,B,D)
    const float* Mask = (const float*)d_in[1];  // (H,S,S)
    const float* gate = (const float*)d_in[2];  // (1,B,1)
    const float* Wi   = (const float*)d_in[3];  // (3D,D)
    const float* bi   = (const float*)d_in[4];  // (3D)
    const float* Wo   = (const float*)d_in[5];  // (D,D)
    const float* bo   = (const float*)d_in[6];  // (D)
    _Float16* ws = (_Float16*)d_ws;
    const size_t plane = (size_t)4 * 8 * 2048 * 64;  // 4,194,304 f16 elems
    _Float16* Qh  = ws;
    _Float16* Kh  = ws + plane;
    _Float16* Vt  = ws + 2 * plane;              // pre-permuted V^T
    _Float16* P1  = ws + 3 * plane;
    _Float16* Xh  = ws + 4 * plane;              // dead after qkv; aliased by P0
    _Float16* Wih = ws + 5 * plane;              // 786,432 (dead after qkv)
    _Float16* Woh = ws + 5 * plane + 786432;     // 262,144 (live until oproj)
    _Float16* P0  = Xh;
    _Float16* P2  = ws + 5 * plane + 1048576;
    _Float16* P3  = P2 + plane;
    float*    Lb  = (float*)(P3 + plane);        // 4*65536 f32

    cvt_f16<<<dim3(2560), 256, 0, stream>>>(X, Wi, Wo, Xh, Wih, Woh);
    qkv_mfma<<<dim3(24, 64), 256, 0, stream>>>(Xh, Wih, bi, gate, Qh, Kh, Vt);
    attn_mfma<<<dim3(1024), 256, 0, stream>>>(Qh, Kh, Vt, Mask, P0, P1, P2, P3, Lb);
    oproj_mfma<<<dim3(8, 64), 256, 0, stream>>>(P0, P1, P2, P3, Lb, Woh, bo, (float*)d_out);
}

// Round 10
// 134.071 us; speedup vs baseline: 4.7399x; 1.5224x over previous
//
#include <hip/hip_runtime.h>
#include <cstdint>
#include <cstddef>

typedef _Float16 half8 __attribute__((ext_vector_type(8)));
typedef _Float16 half4 __attribute__((ext_vector_type(4)));
typedef float f32x4 __attribute__((ext_vector_type(4)));

#define MFMA16(A,B,C) __builtin_amdgcn_mfma_f32_16x16x32_f16(A,B,C,0,0,0)

// global -> LDS direct copy, 16B per lane: lds dest = uniform base + lane*16
__device__ __forceinline__ void gll16(const _Float16* g, _Float16* l) {
    __builtin_amdgcn_global_load_lds(
        (const __attribute__((address_space(1))) void*)g,
        (__attribute__((address_space(3))) void*)l, 16, 0, 0);
}

// ---------------- K0: bulk f32 -> f16 convert (X, Wi, Wo) ----------------
__global__ __launch_bounds__(256) void cvt_f16(
    const float* __restrict__ X, const float* __restrict__ Wi, const float* __restrict__ Wo,
    _Float16* __restrict__ Xh, _Float16* __restrict__ Wih, _Float16* __restrict__ Woh)
{
    const size_t i8 = ((size_t)blockIdx.x * 256 + threadIdx.x) * 8;
    const size_t NX = (size_t)4194304, NWI = 786432;
    const float* src; _Float16* dst; size_t off;
    if (i8 < NX) { src = X; dst = Xh; off = i8; }
    else if (i8 < NX + NWI) { src = Wi; dst = Wih; off = i8 - NX; }
    else { src = Wo; dst = Woh; off = i8 - NX - NWI; }
    f32x4 v0 = *(const f32x4*)(src + off);
    f32x4 v1 = *(const f32x4*)(src + off + 4);
    half8 r;
    r[0]=(_Float16)v0[0]; r[1]=(_Float16)v0[1]; r[2]=(_Float16)v0[2]; r[3]=(_Float16)v0[3];
    r[4]=(_Float16)v1[0]; r[5]=(_Float16)v1[1]; r[6]=(_Float16)v1[2]; r[7]=(_Float16)v1[3];
    *(half8*)(dst + off) = r;
}

// ---------------- K1: QKV projection (f16 MFMA, f16 inputs) ----------------
// V^T written PRE-PERMUTED within each 32-col group: s -> (s&~31)|8g|4hi|j
__global__ __launch_bounds__(256) void qkv_mfma(
    const _Float16* __restrict__ X, const _Float16* __restrict__ W,
    const float* __restrict__ bias, const float* __restrict__ gate,
    _Float16* __restrict__ Qo, _Float16* __restrict__ Ko, _Float16* __restrict__ Vt)
{
    __shared__ _Float16 As[128][72];
    __shared__ _Float16 Bs[64][72];
    const int tid = threadIdx.x;
    const int lane = tid & 63, wv = tid >> 6;
    const int l15 = lane & 15, g = lane >> 4;
    const int wr = wv >> 1, wc = wv & 1;
    const int j0 = blockIdx.x * 64, r0 = blockIdx.y * 128;
    f32x4 acc[4][2] = {};
    const int arow = tid >> 1, ahf = tid & 1;
    const int brow = tid >> 2, bc = tid & 3;
    for (int k0 = 0; k0 < 512; k0 += 64) {
        const _Float16* srca = X + (size_t)(r0 + arow) * 512 + k0 + ahf * 32;
#pragma unroll
        for (int c = 0; c < 4; ++c)
            *(half8*)&As[arow][ahf * 32 + c * 8] = *(const half8*)(srca + c * 8);
        const _Float16* srcb = W + (size_t)(j0 + brow) * 512 + k0 + bc * 16;
#pragma unroll
        for (int c = 0; c < 2; ++c)
            *(half8*)&Bs[brow][bc * 16 + c * 8] = *(const half8*)(srcb + c * 8);
        __syncthreads();
#pragma unroll
        for (int kt = 0; kt < 2; ++kt) {
            half8 bf0 = *(half8*)&Bs[32 * wc + l15][kt * 32 + g * 8];
            half8 bf1 = *(half8*)&Bs[32 * wc + 16 + l15][kt * 32 + g * 8];
#pragma unroll
            for (int ri = 0; ri < 4; ++ri) {
                half8 af = *(half8*)&As[64 * wr + 16 * ri + l15][kt * 32 + g * 8];
                acc[ri][0] = MFMA16(af, bf0, acc[ri][0]);
                acc[ri][1] = MFMA16(af, bf1, acc[ri][1]);
            }
        }
        __syncthreads();
    }
#pragma unroll
    for (int ri = 0; ri < 4; ++ri) {
#pragma unroll
        for (int cj = 0; cj < 2; ++cj) {
            const int col = j0 + 32 * wc + 16 * cj + l15;
            const int sec = col >> 9, hh = (col >> 6) & 7, d = col & 63;
            const float bv = bias[col];
#pragma unroll
            for (int r = 0; r < 4; ++r) {
                const int row = r0 + 64 * wr + 16 * ri + 4 * g + r;
                const int b = row & 3, s = row >> 2;
                const float v = acc[ri][cj][r];
                if (sec == 0)
                    Qo[((size_t)(b * 8 + hh) * 2048 + s) * 64 + d] = (_Float16)((v + bv) * 0.125f);
                else if (sec == 1)
                    Ko[((size_t)(b * 8 + hh) * 2048 + s) * 64 + d] = (_Float16)(v + bv);
                else {
                    const int ps = (s & ~31) | ((s & 12) << 1) | ((s & 16) >> 2) | (s & 3);
                    Vt[((size_t)(b * 8 + hh) * 64 + d) * 2048 + ps] = (_Float16)(v * gate[b] + bv);
                }
            }
        }
    }
}

// ---------------- K2: flash attention, mask shared across all 4 batches ----------
// Block = (h, q64-group, kv-quarter 512). Wave w: 16 q-rows (qg*64 + w*16), ALL 4 b.
// Per kv32 tile: one mask load pair mc[2] is the MFMA C-init for all 4 batches.
// LDS: K/V tiles for 4 batches, double-buffered (64 KB). Swizzled gll staging:
//   Kl[b][r][blk] = K[t0+r][(blk ^ (r&7))*8]       (8 x 16B blocks / row)
//   Vl[b][d][blk] = V^T[d][t0 + (blk ^ ((d>>1)&3))*8]  (4 x 16B blocks / row)
// bid = qg*32 + h*4 + kvh: blocks sharing (h,kvh) [same K/V] land on one XCD.
__global__ __launch_bounds__(256) void attn_mfma(
    const _Float16* __restrict__ Q, const _Float16* __restrict__ K,
    const _Float16* __restrict__ V, const float* __restrict__ M,
    _Float16* __restrict__ P0, _Float16* __restrict__ P1,
    _Float16* __restrict__ P2, _Float16* __restrict__ P3, float* __restrict__ Lb)
{
    __shared__ _Float16 Kl[2][4][32][64];
    __shared__ _Float16 Vl[2][4][64][32];
    const int tid = threadIdx.x;
    const int lane = tid & 63, w = tid >> 6;
    const int l15 = lane & 15, g = lane >> 4;
    const int bid = blockIdx.x;
    const int kvh = bid & 3, h = (bid >> 2) & 7, qg = bid >> 5;
    const int q0 = qg * 64 + w * 16;
    const _Float16* Qp[4]; const _Float16* Kp[4]; const _Float16* Vp[4];
#pragma unroll
    for (int b = 0; b < 4; ++b) {
        const size_t bh = (size_t)b * 8 + h;
        Qp[b] = Q + bh * 2048 * 64;
        Kp[b] = K + (bh * 2048 + (size_t)kvh * 512) * 64;
        Vp[b] = V + bh * 64 * 2048 + kvh * 512;
    }
    const float* Mp = M + (size_t)h * 2048 * 2048 + kvh * 512;

    // Q fragments: 16 q-rows for each batch
    half8 qf[4][2];
#pragma unroll
    for (int b = 0; b < 4; ++b)
#pragma unroll
        for (int dh = 0; dh < 2; ++dh)
            qf[b][dh] = *(const half8*)(Qp[b] + (size_t)(q0 + l15) * 64 + dh * 32 + g * 8);

    // staging roles: waves 0,1 stage K (2 batches each), waves 2,3 stage V
    const bool stK = (w < 2);
    const int b0 = (w & 1) * 2;
    const int krow = lane >> 3, kblk = lane & 7;     // K: 8 rows x 8 blocks per gll
    const int vrow = lane >> 2, vblk = lane & 3;     // V: 16 rows x 4 blocks per gll
    const int ksw = (kblk ^ (krow & 7)) * 8;
    const int vsw = (vblk ^ ((vrow >> 1) & 3)) * 8;

    // prologue: stage tile 0 into buf 0
    if (stK) {
#pragma unroll
        for (int bb = 0; bb < 2; ++bb)
#pragma unroll
            for (int c = 0; c < 4; ++c)
                gll16(Kp[b0 + bb] + (size_t)(c * 8 + krow) * 64 + ksw,
                      &Kl[0][b0 + bb][c * 8][0]);
    } else {
#pragma unroll
        for (int bb = 0; bb < 2; ++bb)
#pragma unroll
            for (int c = 0; c < 4; ++c)
                gll16(Vp[b0 + bb] + (size_t)(c * 16 + vrow) * 2048 + vsw,
                      &Vl[0][b0 + bb][c * 16][0]);
    }
    // mask for tile 0
    f32x4 mc[2];
#pragma unroll
    for (int mi = 0; mi < 2; ++mi)
        mc[mi] = *(const f32x4*)(Mp + (size_t)(q0 + l15) * 2048 + 16 * mi + 4 * g);

    f32x4 O[4][4] = {};   // [di][b]
    float l[4] = {0.f, 0.f, 0.f, 0.f};
    __syncthreads();

    for (int tl = 0; tl < 16; ++tl) {
        const int cur = tl & 1;
        const int t0 = tl * 32;
        // prefetch next tile K/V into buf^1
        if (tl < 15) {
            const int tg = t0 + 32;
            if (stK) {
#pragma unroll
                for (int bb = 0; bb < 2; ++bb)
#pragma unroll
                    for (int c = 0; c < 4; ++c)
                        gll16(Kp[b0 + bb] + (size_t)(tg + c * 8 + krow) * 64 + ksw,
                              &Kl[cur ^ 1][b0 + bb][c * 8][0]);
            } else {
#pragma unroll
                for (int bb = 0; bb < 2; ++bb)
#pragma unroll
                    for (int c = 0; c < 4; ++c)
                        gll16(Vp[b0 + bb] + (size_t)(c * 16 + vrow) * 2048 + tg + vsw,
                              &Vl[cur ^ 1][b0 + bb][c * 16][0]);
            }
        }

        // QK^T: mask C-init SHARED across batches
        f32x4 St[2][4];
        __builtin_amdgcn_s_setprio(1);
#pragma unroll
        for (int b = 0; b < 4; ++b) {
#pragma unroll
            for (int mi = 0; mi < 2; ++mi) {
                const int row = 16 * mi + l15;
                half8 kf0 = *(half8*)&Kl[cur][b][row][((g) ^ (l15 & 7)) * 8];
                half8 kf1 = *(half8*)&Kl[cur][b][row][((4 + g) ^ (l15 & 7)) * 8];
                St[mi][b] = MFMA16(kf0, qf[b][0], mc[mi]);
                St[mi][b] = MFMA16(kf1, qf[b][1], St[mi][b]);
            }
        }
        __builtin_amdgcn_s_setprio(0);

        // issue next tile's mask loads (consumed next iteration)
        const int tn = ((tl + 1) & 15) * 32;
        f32x4 mn0 = *(const f32x4*)(Mp + (size_t)(q0 + l15) * 2048 + tn + 4 * g);
        f32x4 mn1 = *(const f32x4*)(Mp + (size_t)(q0 + l15) * 2048 + tn + 16 + 4 * g);

        // static softmax partials + P fragments (split k-map {4g+j, 16+4g+(j-4)})
        half8 pf[4];
#pragma unroll
        for (int b = 0; b < 4; ++b) {
            float e0 = __expf(St[0][b][0]), e1 = __expf(St[0][b][1]);
            float e2 = __expf(St[0][b][2]), e3 = __expf(St[0][b][3]);
            float e4 = __expf(St[1][b][0]), e5 = __expf(St[1][b][1]);
            float e6 = __expf(St[1][b][2]), e7 = __expf(St[1][b][3]);
            l[b] += ((e0 + e1) + (e2 + e3)) + ((e4 + e5) + (e6 + e7));
            half8 p;
            p[0] = (_Float16)e0; p[1] = (_Float16)e1; p[2] = (_Float16)e2; p[3] = (_Float16)e3;
            p[4] = (_Float16)e4; p[5] = (_Float16)e5; p[6] = (_Float16)e6; p[7] = (_Float16)e7;
            pf[b] = p;
        }

        // PV: O^T[d][q] += V^T · P^T per batch
        __builtin_amdgcn_s_setprio(1);
#pragma unroll
        for (int b = 0; b < 4; ++b) {
#pragma unroll
            for (int di = 0; di < 4; ++di) {
                const int row = 16 * di + l15;
                half8 vf = *(half8*)&Vl[cur][b][row][(g ^ ((l15 >> 1) & 3)) * 8];
                O[di][b] = MFMA16(vf, pf[b], O[di][b]);
            }
        }
        __builtin_amdgcn_s_setprio(0);

        mc[0] = mn0; mc[1] = mn1;
        __syncthreads();
    }

    // epilogue: per batch, reduce l across g, write normalized partial + l
#pragma unroll
    for (int b = 0; b < 4; ++b) {
        float lt = l[b];
        lt += __shfl_xor(lt, 16);
        lt += __shfl_xor(lt, 32);
        const float inv = 1.0f / lt;
        const int q = q0 + l15;
        const int r = q * 4 + b;
        _Float16* P = (kvh == 0) ? P0 : (kvh == 1) ? P1 : (kvh == 2) ? P2 : P3;
        _Float16* dst = P + (size_t)r * 512 + h * 64;
#pragma unroll
        for (int di = 0; di < 4; ++di) {
            half4 o;
            o[0] = (_Float16)(O[di][b][0] * inv); o[1] = (_Float16)(O[di][b][1] * inv);
            o[2] = (_Float16)(O[di][b][2] * inv); o[3] = (_Float16)(O[di][b][3] * inv);
            *(half4*)(dst + 16 * di + 4 * g) = o;
        }
        if (g == 0)
            Lb[(size_t)kvh * 65536 + r * 8 + h] = lt;
    }
}

// ---------------- K2b: merge the four kv-quarter partials (raw-l weights) ------------
__global__ __launch_bounds__(256) void merge_attn(
    const _Float16* __restrict__ P0, const _Float16* __restrict__ P1,
    const _Float16* __restrict__ P2, const _Float16* __restrict__ P3,
    const float* __restrict__ Lb, _Float16* __restrict__ AO)
{
    const size_t e = ((size_t)blockIdx.x * 256 + threadIdx.x) * 8;
    const int r = (int)(e >> 9);
    const int h = (int)((e & 511) >> 6);
    const int li = r * 8 + h;
    const float l0 = Lb[li], l1 = Lb[65536 + li];
    const float l2 = Lb[131072 + li], l3 = Lb[196608 + li];
    const float inv = 1.0f / (l0 + l1 + l2 + l3);
    const float a0 = l0 * inv, a1 = l1 * inv, a2 = l2 * inv, a3 = l3 * inv;
    half8 x0 = *(const half8*)(P0 + e);
    half8 x1 = *(const half8*)(P1 + e);
    half8 x2 = *(const half8*)(P2 + e);
    half8 x3 = *(const half8*)(P3 + e);
    half8 o;
#pragma unroll
    for (int i = 0; i < 8; ++i)
        o[i] = (_Float16)(a0 * (float)x0[i] + a1 * (float)x1[i]
                        + a2 * (float)x2[i] + a3 * (float)x3[i]);
    *(half8*)(AO + e) = o;
}

// ---------------- K3: output projection (f16 inputs, f32 out) ----------------
__global__ __launch_bounds__(256) void oproj_mfma(
    const _Float16* __restrict__ A, const _Float16* __restrict__ W,
    const float* __restrict__ bias, float* __restrict__ Out)
{
    __shared__ _Float16 As[128][72];
    __shared__ _Float16 Bs[64][72];
    const int tid = threadIdx.x;
    const int lane = tid & 63, wv = tid >> 6;
    const int l15 = lane & 15, g = lane >> 4;
    const int wr = wv >> 1, wc = wv & 1;
    const int j0 = blockIdx.x * 64, r0 = blockIdx.y * 128;
    f32x4 acc[4][2] = {};
    const int arow = tid >> 1, ahf = tid & 1;
    const int brow = tid >> 2, bc = tid & 3;
    for (int k0 = 0; k0 < 512; k0 += 64) {
        const _Float16* srca = A + (size_t)(r0 + arow) * 512 + k0 + ahf * 32;
#pragma unroll
        for (int c = 0; c < 4; ++c)
            *(half8*)&As[arow][ahf * 32 + c * 8] = *(const half8*)(srca + c * 8);
        const _Float16* srcb = W + (size_t)(j0 + brow) * 512 + k0 + bc * 16;
#pragma unroll
        for (int c = 0; c < 2; ++c)
            *(half8*)&Bs[brow][bc * 16 + c * 8] = *(const half8*)(srcb + c * 8);
        __syncthreads();
#pragma unroll
        for (int kt = 0; kt < 2; ++kt) {
            half8 bf0 = *(half8*)&Bs[32 * wc + l15][kt * 32 + g * 8];
            half8 bf1 = *(half8*)&Bs[32 * wc + 16 + l15][kt * 32 + g * 8];
#pragma unroll
            for (int ri = 0; ri < 4; ++ri) {
                half8 af = *(half8*)&As[64 * wr + 16 * ri + l15][kt * 32 + g * 8];
                acc[ri][0] = MFMA16(af, bf0, acc[ri][0]);
                acc[ri][1] = MFMA16(af, bf1, acc[ri][1]);
            }
        }
        __syncthreads();
    }
#pragma unroll
    for (int ri = 0; ri < 4; ++ri) {
#pragma unroll
        for (int cj = 0; cj < 2; ++cj) {
            const int col = j0 + 32 * wc + 16 * cj + l15;
            const float bv = bias[col];
#pragma unroll
            for (int r = 0; r < 4; ++r) {
                const int row = r0 + 64 * wr + 16 * ri + 4 * g + r;
                Out[(size_t)row * 512 + col] = acc[ri][cj][r] + bv;
            }
        }
    }
}

extern "C" void kernel_launch(void* const* d_in, const int* in_sizes, int n_in,
                              void* d_out, int out_size, void* d_ws, size_t ws_size,
                              hipStream_t stream)
{
    (void)in_sizes; (void)n_in; (void)out_size; (void)ws_size;
    const float* X    = (const float*)d_in[0];  // (S,B,D)
    const float* Mask = (const float*)d_in[1];  // (H,S,S)
    const float* gate = (const float*)d_in[2];  // (1,B,1)
    const float* Wi   = (const float*)d_in[3];  // (3D,D)
    const float* bi   = (const float*)d_in[4];  // (3D)
    const float* Wo   = (const float*)d_in[5];  // (D,D)
    const float* bo   = (const float*)d_in[6];  // (D)
    _Float16* ws = (_Float16*)d_ws;
    const size_t plane = (size_t)4 * 8 * 2048 * 64;  // 4,194,304 f16 elems
    _Float16* Qh  = ws;
    _Float16* Kh  = ws + plane;
    _Float16* Vt  = ws + 2 * plane;              // pre-permuted V^T
    _Float16* AO  = ws + 3 * plane;
    _Float16* Xh  = ws + 4 * plane;              // dead after qkv; aliased by P0
    _Float16* Wih = ws + 5 * plane;              // 786,432 (dead after qkv)
    _Float16* Woh = ws + 5 * plane + 786432;     // 262,144 (live until oproj)
    _Float16* P0  = Xh;
    _Float16* P1  = ws + 5 * plane + 1048576;
    _Float16* P2  = P1 + plane;
    _Float16* P3  = P2 + plane;
    float*    Lb  = (float*)(P3 + plane);        // 4*65536 f32

    cvt_f16<<<dim3(2560), 256, 0, stream>>>(X, Wi, Wo, Xh, Wih, Woh);
    qkv_mfma<<<dim3(24, 64), 256, 0, stream>>>(Xh, Wih, bi, gate, Qh, Kh, Vt);
    attn_mfma<<<dim3(1024), 256, 0, stream>>>(Qh, Kh, Vt, Mask, P0, P1, P2, P3, Lb);
    merge_attn<<<dim3(2048), 256, 0, stream>>>(P0, P1, P2, P3, Lb, AO);
    oproj_mfma<<<dim3(8, 64), 256, 0, stream>>>(AO, Woh, bo, (float*)d_out);
}